// Round 1
// baseline (3588.265 us; speedup 1.0000x reference)
//
#include <hip/hip_runtime.h>

typedef __attribute__((ext_vector_type(8))) short bf16x8;
typedef __attribute__((ext_vector_type(4))) short bf16x4;
typedef __attribute__((ext_vector_type(4))) float f32x4;

__device__ __forceinline__ unsigned short f2bf(float f) {
  unsigned int u = __float_as_uint(f);
  u += 0x7fffu + ((u >> 16) & 1u);   // RNE
  return (unsigned short)(u >> 16);
}

// ---------------- degree / norm ----------------
__global__ void k_deg(const int* __restrict__ ei, int* __restrict__ deg, int E) {
  int e = blockIdx.x * blockDim.x + threadIdx.x;
  if (e < E) atomicAdd(&deg[ei[E + e]], 1);   // in-degree over dst
}

__global__ void k_norm(const int* __restrict__ deg, float* __restrict__ nrm, int n) {
  int i = blockIdx.x * blockDim.x + threadIdx.x;
  if (i < n) nrm[i] = rsqrtf(fmaxf((float)deg[i], 1.f));
}

// ---------------- exclusive scan (3-kernel hierarchical) ----------------
__global__ void k_scan1(const int* __restrict__ deg, int* __restrict__ offs,
                        int* __restrict__ bsum, int n) {
  __shared__ int sm[1024];
  int t = threadIdx.x;
  int gid = blockIdx.x * 1024 + t;
  int v = (gid < n) ? deg[gid] : 0;
  sm[t] = v;
  __syncthreads();
  for (int off = 1; off < 1024; off <<= 1) {
    int x = (t >= off) ? sm[t - off] : 0;
    __syncthreads();
    sm[t] += x;
    __syncthreads();
  }
  if (gid < n) offs[gid] = sm[t] - v;           // exclusive within block
  if (t == 1023) bsum[blockIdx.x] = sm[1023];   // block total
}

__global__ void k_scan2(int* __restrict__ bsum, int nb) {
  __shared__ int sm[128];
  int t = threadIdx.x;
  int v = (t < nb) ? bsum[t] : 0;
  sm[t] = v;
  __syncthreads();
  for (int off = 1; off < 128; off <<= 1) {
    int x = (t >= off) ? sm[t - off] : 0;
    __syncthreads();
    sm[t] += x;
    __syncthreads();
  }
  if (t < nb) bsum[t] = sm[t] - v;     // exclusive block offsets
  if (t == 127) bsum[nb] = sm[127];    // grand total (= E)
}

__global__ void k_scan3(int* __restrict__ offs, const int* __restrict__ bsum, int n) {
  int gid = blockIdx.x * 1024 + threadIdx.x;
  if (gid < n) offs[gid] += bsum[blockIdx.x];
  if (gid == 0) offs[n] = bsum[gridDim.x];
}

// ---------------- CSR scatter ----------------
__global__ void k_scatter(const int* __restrict__ ei, const int* __restrict__ offs,
                          int* __restrict__ cursor, int* __restrict__ csr_src, int E) {
  int e = blockIdx.x * blockDim.x + threadIdx.x;
  if (e < E) {
    int s = ei[e], d = ei[E + e];
    int pos = atomicAdd(&cursor[d], 1);
    csr_src[offs[d] + pos] = s;
  }
}

// ---------------- fused dense front-end ----------------
// Computes, per 64-node tile: C = X @ [W1 | Wy]  (bf16 MFMA, swapped orientation:
// D = W^T · X^T so fragments read contiguously from [row][k] LDS), then
// h = relu(.+b1) -> LDS bf16, logits = softmax(.), h0 = h @ W2 + b2.
#define NCOMB 192
#define SSTR 40     // 32 k + 8 pad (bank rotate)
#define HSTR 136    // 128 k + 8 pad

__global__ __launch_bounds__(256) void k_transform(
    const float* __restrict__ X, const float* __restrict__ W1,
    const float* __restrict__ b1, const float* __restrict__ W2,
    const float* __restrict__ b2, const float* __restrict__ Wy,
    float* __restrict__ h0, float* __restrict__ logits, int n)
{
  __shared__ short Xs[64 * SSTR];        // [m][k]
  __shared__ short Ws[NCOMB * SSTR];     // [j][k]  (= W^T chunk)
  __shared__ short Hs[64 * HSTR];        // [m][j]  h in bf16
  __shared__ short W2s[64 * HSTR];       // [j2][k2] (= W2^T)

  const int tid = threadIdx.x;
  const int w = tid >> 6;       // wave id: m-subtile
  const int lane = tid & 63;
  const int c = lane & 15;      // MFMA row/col index
  const int g = lane >> 4;      // k-group / reg-group
  const int m0 = blockIdx.x * 64;

  f32x4 zero4 = {0.f, 0.f, 0.f, 0.f};
  f32x4 acc[12];
#pragma unroll
  for (int i = 0; i < 12; ++i) acc[i] = zero4;

  // stage W2^T once
#pragma unroll
  for (int i = 0; i < 32; ++i) {
    int idx = tid + i * 256;            // 0..8191
    int k2 = idx >> 6, j2 = idx & 63;
    W2s[j2 * HSTR + k2] = (short)f2bf(W2[idx]);
  }

  const int xr = tid >> 2;            // 0..63
  const int xc = (tid & 3) * 8;       // 0,8,16,24
  const int xrow = m0 + xr;

  for (int kk = 0; kk < 512; kk += 32) {
    // stage X tile (f32 -> bf16)
    float v[8];
    if (xrow < n) {
      const float4* p = (const float4*)(X + (size_t)xrow * 512 + kk + xc);
      float4 a0 = p[0], a1 = p[1];
      v[0]=a0.x; v[1]=a0.y; v[2]=a0.z; v[3]=a0.w;
      v[4]=a1.x; v[5]=a1.y; v[6]=a1.z; v[7]=a1.w;
    } else {
#pragma unroll
      for (int i = 0; i < 8; ++i) v[i] = 0.f;
    }
    {
      short* dst = &Xs[xr * SSTR + xc];
#pragma unroll
      for (int i = 0; i < 8; ++i) dst[i] = (short)f2bf(v[i]);
    }
    // stage [W1|Wy]^T chunk: 6144 elems, coalesced reads, scattered 2B LDS writes
#pragma unroll
    for (int i = 0; i < 24; ++i) {
      int idx = tid + i * 256;          // 0..6143
      int k = idx / NCOMB;
      int j = idx - k * NCOMB;
      float wv = (j < 128) ? W1[(size_t)(kk + k) * 128 + j]
                           : Wy[(size_t)(kk + k) * 64 + (j - 128)];
      Ws[j * SSTR + k] = (short)f2bf(wv);
    }
    __syncthreads();
    bf16x8 bx = *(const bf16x8*)&Xs[(w * 16 + c) * SSTR + g * 8];
#pragma unroll
    for (int jt = 0; jt < 12; ++jt) {
      bf16x8 aw = *(const bf16x8*)&Ws[(jt * 16 + c) * SSTR + g * 8];
      acc[jt] = __builtin_amdgcn_mfma_f32_16x16x32_bf16(aw, bx, acc[jt], 0, 0, 0);
    }
    __syncthreads();
  }

  const int m = w * 16 + c;       // node within tile (D col = lane&15)
  const int grow = m0 + m;

  // h = relu(. + b1) -> Hs bf16   (D row = g*4+q within j-tile)
#pragma unroll
  for (int jt = 0; jt < 8; ++jt) {
    int jb = jt * 16 + g * 4;
    bf16x4 hv;
#pragma unroll
    for (int q = 0; q < 4; ++q) {
      float hvf = fmaxf(acc[jt][q] + b1[jb + q], 0.f);
      hv[q] = (short)f2bf(hvf);
    }
    *(bf16x4*)&Hs[m * HSTR + jb] = hv;
  }

  // softmax over the 64 logit cols (tiles 8..11); node m's values live in the
  // 4 lanes sharing c (g=0..3) -> reduce with shfl_xor 16,32
  float lv[16];
  float mx = -3.4e38f;
#pragma unroll
  for (int t = 0; t < 4; ++t) {
#pragma unroll
    for (int q = 0; q < 4; ++q) {
      float vv = acc[8 + t][q];
      lv[t * 4 + q] = vv;
      mx = fmaxf(mx, vv);
    }
  }
  mx = fmaxf(mx, __shfl_xor(mx, 16, 64));
  mx = fmaxf(mx, __shfl_xor(mx, 32, 64));
  float sum = 0.f;
#pragma unroll
  for (int i = 0; i < 16; ++i) { lv[i] = __expf(lv[i] - mx); sum += lv[i]; }
  sum += __shfl_xor(sum, 16, 64);
  sum += __shfl_xor(sum, 32, 64);
  float inv = 1.f / sum;
  if (grow < n) {
#pragma unroll
    for (int t = 0; t < 4; ++t) {
      float4 o;
      o.x = lv[t*4+0]*inv; o.y = lv[t*4+1]*inv;
      o.z = lv[t*4+2]*inv; o.w = lv[t*4+3]*inv;
      *(float4*)(logits + (size_t)grow * 64 + t * 16 + g * 4) = o;
    }
  }
  __syncthreads();   // Hs complete

  // phase 2: h0 = Hs @ W2 + b2  (K=128)
  f32x4 acc2[4];
#pragma unroll
  for (int i = 0; i < 4; ++i) acc2[i] = zero4;
#pragma unroll
  for (int kk2 = 0; kk2 < 4; ++kk2) {
    bf16x8 bh = *(const bf16x8*)&Hs[m * HSTR + kk2 * 32 + g * 8];
#pragma unroll
    for (int j2t = 0; j2t < 4; ++j2t) {
      bf16x8 a2 = *(const bf16x8*)&W2s[(j2t * 16 + c) * HSTR + kk2 * 32 + g * 8];
      acc2[j2t] = __builtin_amdgcn_mfma_f32_16x16x32_bf16(a2, bh, acc2[j2t], 0, 0, 0);
    }
  }
  if (grow < n) {
#pragma unroll
    for (int j2t = 0; j2t < 4; ++j2t) {
      int jb = j2t * 16 + g * 4;
      float4 o;
      o.x = acc2[j2t][0] + b2[jb+0];
      o.y = acc2[j2t][1] + b2[jb+1];
      o.z = acc2[j2t][2] + b2[jb+2];
      o.w = acc2[j2t][3] + b2[jb+3];
      *(float4*)(h0 + (size_t)grow * 64 + jb) = o;
    }
  }
}

// ---------------- fused gated propagation step ----------------
// One wave per dst node, lane = class. Fuses both SpMMs + gate + update.
__global__ __launch_bounds__(256) void k_prop(
    const int* __restrict__ offs, const int* __restrict__ csr_src,
    const float* __restrict__ nrm,
    const float* __restrict__ lg_in, float* __restrict__ lg_out,
    const float* __restrict__ hc_in, const float* __restrict__ h0,
    float* __restrict__ hc_out, int n)
{
  int lane = threadIdx.x & 63;
  int node = blockIdx.x * 4 + (threadIdx.x >> 6);
  if (node >= n) return;
  int beg = offs[node], end = offs[node + 1];
  float nd = nrm[node];
  float acc_lg = 0.f, acc_h = 0.f;
  for (int e = beg; e < end; ++e) {
    int s = csr_src[e];                    // wave-uniform
    float w = nd * nrm[s];
    acc_lg = fmaf(w, lg_in[(size_t)s * 64 + lane], acc_lg);
    acc_h  = fmaf(w, hc_in[(size_t)s * 64 + lane], acc_h);
  }
  size_t base = (size_t)node * 64 + lane;
  float p = lg_in[base] * acc_lg;
#pragma unroll
  for (int off = 32; off >= 1; off >>= 1) p += __shfl_xor(p, off, 64);
  float z = 1.f / (1.f + __expf(-p));
  hc_out[base] = z * acc_h + (1.f - z) * h0[base];
  lg_out[base] = acc_lg;
}

// ---------------- launch ----------------
extern "C" void kernel_launch(void* const* d_in, const int* in_sizes, int n_in,
                              void* d_out, int out_size, void* d_ws, size_t ws_size,
                              hipStream_t stream) {
  (void)n_in; (void)out_size; (void)ws_size;
  const float* X  = (const float*)d_in[0];
  const float* W1 = (const float*)d_in[1];
  const float* b1 = (const float*)d_in[2];
  const float* W2 = (const float*)d_in[3];
  const float* b2 = (const float*)d_in[4];
  const float* Wy = (const float*)d_in[5];
  const int*   ei = (const int*)d_in[6];
  const int N = in_sizes[0] / 512;
  const int E = in_sizes[6] / 2;

  char* p = (char*)d_ws;
  auto alloc = [&](size_t bytes) -> char* {
    char* r = p; p += (bytes + 255) & ~(size_t)255; return r;
  };
  int*   deg     = (int*)  alloc((size_t)N * 4);
  float* nrm     = (float*)alloc((size_t)N * 4);
  int*   offs    = (int*)  alloc((size_t)(N + 1) * 4);
  int*   cursor  = (int*)  alloc((size_t)N * 4);
  int*   bsum    = (int*)  alloc(1024);
  int*   csr_src = (int*)  alloc((size_t)E * 4);
  float* h0      = (float*)alloc((size_t)N * 64 * 4);
  float* lgA     = (float*)alloc((size_t)N * 64 * 4);
  float* lgB     = (float*)alloc((size_t)N * 64 * 4);
  float* hcA     = (float*)alloc((size_t)N * 64 * 4);
  float* hcB     = (float*)d_out;   // final step lands in d_out

  hipMemsetAsync(deg, 0, (size_t)N * 4, stream);
  hipMemsetAsync(cursor, 0, (size_t)N * 4, stream);

  const int tpb = 256;
  k_deg<<<(E + tpb - 1) / tpb, tpb, 0, stream>>>(ei, deg, E);
  k_norm<<<(N + tpb - 1) / tpb, tpb, 0, stream>>>(deg, nrm, N);
  int nb = (N + 1023) / 1024;
  k_scan1<<<nb, 1024, 0, stream>>>(deg, offs, bsum, N);
  k_scan2<<<1, 128, 0, stream>>>(bsum, nb);
  k_scan3<<<nb, 1024, 0, stream>>>(offs, bsum, N);
  k_scatter<<<(E + tpb - 1) / tpb, tpb, 0, stream>>>(ei, offs, cursor, csr_src, E);
  k_transform<<<(N + 63) / 64, 256, 0, stream>>>(X, W1, b1, W2, b2, Wy, h0, lgA, N);

  float* hbuf[2] = {hcA, hcB};
  float* lbuf[2] = {lgA, lgB};
  for (int k = 0; k < 10; ++k) {
    const float* lin  = lbuf[k & 1];
    float*       lout = lbuf[(k + 1) & 1];
    const float* hin  = (k == 0) ? h0 : hbuf[(k - 1) & 1];
    float*       hout = hbuf[k & 1];
    k_prop<<<(N + 3) / 4, tpb, 0, stream>>>(offs, csr_src, nrm, lin, lout, hin, h0, hout, N);
  }
}

// Round 2
// 1656.959 us; speedup vs baseline: 2.1656x; 2.1656x over previous
//
#include <hip/hip_runtime.h>

typedef __attribute__((ext_vector_type(8))) short bf16x8;
typedef __attribute__((ext_vector_type(4))) short bf16x4;
typedef __attribute__((ext_vector_type(4))) float f32x4;
typedef __attribute__((ext_vector_type(4))) unsigned int u32x4;

__device__ __forceinline__ unsigned short f2bf(float f) {
  unsigned int u = __float_as_uint(f);
  u += 0x7fffu + ((u >> 16) & 1u);   // RNE
  return (unsigned short)(u >> 16);
}
__device__ __forceinline__ float bflo(unsigned int w) { return __uint_as_float(w << 16); }
__device__ __forceinline__ float bfhi(unsigned int w) { return __uint_as_float(w & 0xffff0000u); }

// ---------------- degree / norm ----------------
__global__ void k_deg(const int* __restrict__ ei, int* __restrict__ deg, int E) {
  int e = blockIdx.x * blockDim.x + threadIdx.x;
  if (e < E) atomicAdd(&deg[ei[E + e]], 1);   // in-degree over dst
}

__global__ void k_norm(const int* __restrict__ deg, float* __restrict__ nrm, int n) {
  int i = blockIdx.x * blockDim.x + threadIdx.x;
  if (i < n) nrm[i] = rsqrtf(fmaxf((float)deg[i], 1.f));
}

// ---------------- exclusive scan (3-kernel hierarchical) ----------------
__global__ void k_scan1(const int* __restrict__ deg, int* __restrict__ offs,
                        int* __restrict__ bsum, int n) {
  __shared__ int sm[1024];
  int t = threadIdx.x;
  int gid = blockIdx.x * 1024 + t;
  int v = (gid < n) ? deg[gid] : 0;
  sm[t] = v;
  __syncthreads();
  for (int off = 1; off < 1024; off <<= 1) {
    int x = (t >= off) ? sm[t - off] : 0;
    __syncthreads();
    sm[t] += x;
    __syncthreads();
  }
  if (gid < n) offs[gid] = sm[t] - v;           // exclusive within block
  if (t == 1023) bsum[blockIdx.x] = sm[1023];   // block total
}

__global__ void k_scan2(int* __restrict__ bsum, int nb) {
  __shared__ int sm[128];
  int t = threadIdx.x;
  int v = (t < nb) ? bsum[t] : 0;
  sm[t] = v;
  __syncthreads();
  for (int off = 1; off < 128; off <<= 1) {
    int x = (t >= off) ? sm[t - off] : 0;
    __syncthreads();
    sm[t] += x;
    __syncthreads();
  }
  if (t < nb) bsum[t] = sm[t] - v;     // exclusive block offsets
  if (t == 127) bsum[nb] = sm[127];    // grand total (= E)
}

__global__ void k_scan3(int* __restrict__ offs, const int* __restrict__ bsum, int n) {
  int gid = blockIdx.x * 1024 + threadIdx.x;
  if (gid < n) offs[gid] += bsum[blockIdx.x];
  if (gid == 0) offs[n] = bsum[gridDim.x];
}

// ---------------- CSR scatter ----------------
__global__ void k_scatter(const int* __restrict__ ei, const int* __restrict__ offs,
                          int* __restrict__ cursor, int* __restrict__ csr_src, int E) {
  int e = blockIdx.x * blockDim.x + threadIdx.x;
  if (e < E) {
    int s = ei[e], d = ei[E + e];
    int pos = atomicAdd(&cursor[d], 1);
    csr_src[offs[d] + pos] = s;
  }
}

// ---------------- fused dense front-end ----------------
// Per 64-node tile: C = X @ [W1 | Wy] (bf16 MFMA, swapped orientation), then
// h = relu(.+b1) -> LDS bf16, logits = softmax(.), h0 = h @ W2 + b2.
// Outputs: h0b (bf16 [N][64]) and pk0 (uint [N][64]: lo=nrm*logits bf16,
// hi=nrm*h0 bf16) -- the norm-prescaled packed state for propagation.
#define NCOMB 192
#define SSTR 40     // 32 k + 8 pad (bank rotate)
#define HSTR 136    // 128 k + 8 pad

__global__ __launch_bounds__(256) void k_transform(
    const float* __restrict__ X, const float* __restrict__ W1,
    const float* __restrict__ b1, const float* __restrict__ W2,
    const float* __restrict__ b2, const float* __restrict__ Wy,
    const float* __restrict__ nrm,
    unsigned int* __restrict__ pk0, unsigned short* __restrict__ h0b, int n)
{
  __shared__ short Xs[64 * SSTR];        // [m][k]
  __shared__ short Ws[NCOMB * SSTR];     // [j][k]  (= W^T chunk)
  __shared__ short Hs[64 * HSTR];        // [m][j]  h in bf16
  __shared__ short W2s[64 * HSTR];       // [j2][k2] (= W2^T)

  const int tid = threadIdx.x;
  const int w = tid >> 6;       // wave id: m-subtile
  const int lane = tid & 63;
  const int c = lane & 15;      // MFMA row/col index
  const int g = lane >> 4;      // k-group / reg-group
  const int m0 = blockIdx.x * 64;

  f32x4 zero4 = {0.f, 0.f, 0.f, 0.f};
  f32x4 acc[12];
#pragma unroll
  for (int i = 0; i < 12; ++i) acc[i] = zero4;

  // stage W2^T once
#pragma unroll
  for (int i = 0; i < 32; ++i) {
    int idx = tid + i * 256;            // 0..8191
    int k2 = idx >> 6, j2 = idx & 63;
    W2s[j2 * HSTR + k2] = (short)f2bf(W2[idx]);
  }

  const int xr = tid >> 2;            // 0..63
  const int xc = (tid & 3) * 8;       // 0,8,16,24
  const int xrow = m0 + xr;

  for (int kk = 0; kk < 512; kk += 32) {
    // stage X tile (f32 -> bf16)
    float v[8];
    if (xrow < n) {
      const float4* p = (const float4*)(X + (size_t)xrow * 512 + kk + xc);
      float4 a0 = p[0], a1 = p[1];
      v[0]=a0.x; v[1]=a0.y; v[2]=a0.z; v[3]=a0.w;
      v[4]=a1.x; v[5]=a1.y; v[6]=a1.z; v[7]=a1.w;
    } else {
#pragma unroll
      for (int i = 0; i < 8; ++i) v[i] = 0.f;
    }
    {
      short* dst = &Xs[xr * SSTR + xc];
#pragma unroll
      for (int i = 0; i < 8; ++i) dst[i] = (short)f2bf(v[i]);
    }
    // stage [W1|Wy]^T chunk
#pragma unroll
    for (int i = 0; i < 24; ++i) {
      int idx = tid + i * 256;          // 0..6143
      int k = idx / NCOMB;
      int j = idx - k * NCOMB;
      float wv = (j < 128) ? W1[(size_t)(kk + k) * 128 + j]
                           : Wy[(size_t)(kk + k) * 64 + (j - 128)];
      Ws[j * SSTR + k] = (short)f2bf(wv);
    }
    __syncthreads();
    bf16x8 bx = *(const bf16x8*)&Xs[(w * 16 + c) * SSTR + g * 8];
#pragma unroll
    for (int jt = 0; jt < 12; ++jt) {
      bf16x8 aw = *(const bf16x8*)&Ws[(jt * 16 + c) * SSTR + g * 8];
      acc[jt] = __builtin_amdgcn_mfma_f32_16x16x32_bf16(aw, bx, acc[jt], 0, 0, 0);
    }
    __syncthreads();
  }

  const int m = w * 16 + c;       // node within tile (D col = lane&15)
  const int grow = m0 + m;

  // h = relu(. + b1) -> Hs bf16   (D row = g*4+q within j-tile)
#pragma unroll
  for (int jt = 0; jt < 8; ++jt) {
    int jb = jt * 16 + g * 4;
    bf16x4 hv;
#pragma unroll
    for (int q = 0; q < 4; ++q) {
      float hvf = fmaxf(acc[jt][q] + b1[jb + q], 0.f);
      hv[q] = (short)f2bf(hvf);
    }
    *(bf16x4*)&Hs[m * HSTR + jb] = hv;
  }

  // softmax over the 64 logit cols (tiles 8..11); node m's values live in the
  // 4 lanes sharing c (g=0..3) -> reduce with shfl_xor 16,32
  float lv[16];
  float mx = -3.4e38f;
#pragma unroll
  for (int t = 0; t < 4; ++t) {
#pragma unroll
    for (int q = 0; q < 4; ++q) {
      float vv = acc[8 + t][q];
      lv[t * 4 + q] = vv;
      mx = fmaxf(mx, vv);
    }
  }
  mx = fmaxf(mx, __shfl_xor(mx, 16, 64));
  mx = fmaxf(mx, __shfl_xor(mx, 32, 64));
  float sum = 0.f;
#pragma unroll
  for (int i = 0; i < 16; ++i) { lv[i] = __expf(lv[i] - mx); sum += lv[i]; }
  sum += __shfl_xor(sum, 16, 64);
  sum += __shfl_xor(sum, 32, 64);
  float inv = 1.f / sum;
  __syncthreads();   // Hs complete

  // phase 2: h0 = Hs @ W2 + b2  (K=128)
  f32x4 acc2[4];
#pragma unroll
  for (int i = 0; i < 4; ++i) acc2[i] = zero4;
#pragma unroll
  for (int kk2 = 0; kk2 < 4; ++kk2) {
    bf16x8 bh = *(const bf16x8*)&Hs[m * HSTR + kk2 * 32 + g * 8];
#pragma unroll
    for (int j2t = 0; j2t < 4; ++j2t) {
      bf16x8 a2 = *(const bf16x8*)&W2s[(j2t * 16 + c) * HSTR + kk2 * 32 + g * 8];
      acc2[j2t] = __builtin_amdgcn_mfma_f32_16x16x32_bf16(a2, bh, acc2[j2t], 0, 0, 0);
    }
  }

  if (grow < n) {
    float nd = nrm[grow];
#pragma unroll
    for (int t = 0; t < 4; ++t) {
      int cb = t * 16 + g * 4;
      u32x4 pkv;
      bf16x4 hb;
#pragma unroll
      for (int q = 0; q < 4; ++q) {
        float lg  = lv[t * 4 + q] * inv;        // softmax prob
        float h0v = acc2[t][q] + b2[cb + q];
        hb[q]  = (short)f2bf(h0v);
        pkv[q] = ((unsigned)f2bf(nd * h0v) << 16) | (unsigned)f2bf(nd * lg);
      }
      *(u32x4*)(pk0 + (size_t)grow * 64 + cb) = pkv;
      *(bf16x4*)(h0b + (size_t)grow * 64 + cb) = hb;
    }
  }
}

// ---------------- fused gated propagation step ----------------
// One wave per dst node, lane = class. State is norm-prescaled and bf16-packed:
// pk[i][c] = (bf16(nrm[i]*hc[i][c]) << 16) | bf16(nrm[i]*lg[i][c]).
// Inner loop is pure adds: weights are folded into the node scaling.
__global__ __launch_bounds__(256) void k_prop(
    const int* __restrict__ offs, const int* __restrict__ csr_src,
    const unsigned int* __restrict__ pk_in, unsigned int* __restrict__ pk_out,
    const unsigned short* __restrict__ h0b, const float* __restrict__ nrm,
    float* __restrict__ final_out, int n, int last)
{
  const int lane = threadIdx.x & 63;
  const int node = blockIdx.x * 4 + (threadIdx.x >> 6);
  if (node >= n) return;
  const int beg = offs[node], end = offs[node + 1];

  float aL0 = 0.f, aL1 = 0.f, aH0 = 0.f, aH1 = 0.f;
  int e = beg;
  for (; e + 4 <= end; e += 4) {
    int s0 = csr_src[e + 0];
    int s1 = csr_src[e + 1];
    int s2 = csr_src[e + 2];
    int s3 = csr_src[e + 3];
    unsigned w0 = pk_in[(size_t)s0 * 64 + lane];
    unsigned w1 = pk_in[(size_t)s1 * 64 + lane];
    unsigned w2 = pk_in[(size_t)s2 * 64 + lane];
    unsigned w3 = pk_in[(size_t)s3 * 64 + lane];
    aL0 += bflo(w0) + bflo(w1);
    aL1 += bflo(w2) + bflo(w3);
    aH0 += bfhi(w0) + bfhi(w1);
    aH1 += bfhi(w2) + bfhi(w3);
  }
  for (; e < end; ++e) {
    unsigned w = pk_in[(size_t)csr_src[e] * 64 + lane];
    aL0 += bflo(w);
    aH0 += bfhi(w);
  }
  float aL = aL0 + aL1;   // = sum_s nrm[s]*lg[s][lane]
  float aH = aH0 + aH1;   // = sum_s nrm[s]*hc[s][lane]

  size_t base = (size_t)node * 64 + lane;
  // gate: sum_c lg[d][c]*agg_lg[d][c] = sum_c L[d][c]*aL[c]  (nrm[d] cancels)
  float p = bflo(pk_in[base]) * aL;
#pragma unroll
  for (int off = 32; off >= 1; off >>= 1) p += __shfl_xor(p, off, 64);
  float z = 1.f / (1.f + __expf(-p));

  float nd = nrm[node];
  float h0v = __uint_as_float((unsigned)h0b[base] << 16);
  float hn = z * nd * aH + (1.f - z) * h0v;

  if (last) {
    final_out[base] = hn;
  } else {
    // L_out = nrm[d]*agg_lg = nrm[d]^2*aL ; H_out = nrm[d]*h_new
    pk_out[base] = ((unsigned)f2bf(nd * hn) << 16) | (unsigned)f2bf(nd * nd * aL);
  }
}

// ---------------- launch ----------------
extern "C" void kernel_launch(void* const* d_in, const int* in_sizes, int n_in,
                              void* d_out, int out_size, void* d_ws, size_t ws_size,
                              hipStream_t stream) {
  (void)n_in; (void)out_size; (void)ws_size;
  const float* X  = (const float*)d_in[0];
  const float* W1 = (const float*)d_in[1];
  const float* b1 = (const float*)d_in[2];
  const float* W2 = (const float*)d_in[3];
  const float* b2 = (const float*)d_in[4];
  const float* Wy = (const float*)d_in[5];
  const int*   ei = (const int*)d_in[6];
  const int N = in_sizes[0] / 512;
  const int E = in_sizes[6] / 2;

  char* p = (char*)d_ws;
  auto alloc = [&](size_t bytes) -> char* {
    char* r = p; p += (bytes + 255) & ~(size_t)255; return r;
  };
  int*            deg     = (int*)           alloc((size_t)N * 4);
  float*          nrm     = (float*)         alloc((size_t)N * 4);
  int*            offs    = (int*)           alloc((size_t)(N + 1) * 4);
  int*            cursor  = (int*)           alloc((size_t)N * 4);
  int*            bsum    = (int*)           alloc(1024);
  int*            csr_src = (int*)           alloc((size_t)E * 4);
  unsigned int*   pkA     = (unsigned int*)  alloc((size_t)N * 64 * 4);
  unsigned int*   pkB     = (unsigned int*)  alloc((size_t)N * 64 * 4);
  unsigned short* h0b     = (unsigned short*)alloc((size_t)N * 64 * 2);

  hipMemsetAsync(deg, 0, (size_t)N * 4, stream);
  hipMemsetAsync(cursor, 0, (size_t)N * 4, stream);

  const int tpb = 256;
  k_deg<<<(E + tpb - 1) / tpb, tpb, 0, stream>>>(ei, deg, E);
  k_norm<<<(N + tpb - 1) / tpb, tpb, 0, stream>>>(deg, nrm, N);
  int nb = (N + 1023) / 1024;
  k_scan1<<<nb, 1024, 0, stream>>>(deg, offs, bsum, N);
  k_scan2<<<1, 128, 0, stream>>>(bsum, nb);
  k_scan3<<<nb, 1024, 0, stream>>>(offs, bsum, N);
  k_scatter<<<(E + tpb - 1) / tpb, tpb, 0, stream>>>(ei, offs, cursor, csr_src, E);
  k_transform<<<(N + 63) / 64, 256, 0, stream>>>(X, W1, b1, W2, b2, Wy, nrm, pkA, h0b, N);

  for (int k = 0; k < 10; ++k) {
    const unsigned int* in  = (k & 1) ? pkB : pkA;
    unsigned int*       out = (k & 1) ? pkA : pkB;
    k_prop<<<(N + 3) / 4, tpb, 0, stream>>>(offs, csr_src, in, out, h0b, nrm,
                                            (float*)d_out, N, (k == 9) ? 1 : 0);
  }
}

// Round 4
// 1340.871 us; speedup vs baseline: 2.6761x; 1.2357x over previous
//
#include <hip/hip_runtime.h>

typedef __attribute__((ext_vector_type(8))) short bf16x8;
typedef __attribute__((ext_vector_type(4))) short bf16x4;
typedef __attribute__((ext_vector_type(4))) float f32x4;
typedef __attribute__((ext_vector_type(4))) unsigned int u32x4;

__device__ __forceinline__ unsigned short f2bf(float f) {
  unsigned int u = __float_as_uint(f);
  u += 0x7fffu + ((u >> 16) & 1u);   // RNE
  return (unsigned short)(u >> 16);
}
__device__ __forceinline__ float bflo(unsigned int w) { return __uint_as_float(w << 16); }
__device__ __forceinline__ float bfhi(unsigned int w) { return __uint_as_float(w & 0xffff0000u); }

// Swizzled LDS address: dense row stride + XOR((row&7)<<4) -> <=2-way conflicts.
__device__ __forceinline__ short* ldsp(short* base, int row, int rowbytes, int colshort) {
  int off = row * rowbytes + colshort * 2;
  off ^= ((row & 7) << 4);
  return (short*)((char*)base + off);
}

#define CHUNK 8192
#define NBMAX 512

// ---------------- CSR build: bucket histogram ----------------
__global__ __launch_bounds__(256) void k_bhist(const int* __restrict__ ei, int E, int NB,
                                               int* __restrict__ gcnt, int* __restrict__ wghist) {
  __shared__ int h[NBMAX];
  for (int t = threadIdx.x; t < NB; t += 256) h[t] = 0;
  __syncthreads();
  int base = blockIdx.x * CHUNK;
#pragma unroll
  for (int i = 0; i < CHUNK / 256; ++i) {
    int e = base + i * 256 + threadIdx.x;
    if (e < E) atomicAdd(&h[ei[E + e] >> 8], 1);
  }
  __syncthreads();
  for (int t = threadIdx.x; t < NB; t += 256) {
    int c = h[t];
    wghist[blockIdx.x * NBMAX + t] = c;
    if (c) atomicAdd(&gcnt[t], c);
  }
}

// ---------------- bucket-count scan ----------------
__global__ void k_bscan(const int* __restrict__ gcnt, int* __restrict__ bbase,
                        int* __restrict__ gcur, int* __restrict__ offs, int NB, int N) {
  __shared__ int sm[512];
  int t = threadIdx.x;
  int v = (t < NB) ? gcnt[t] : 0;
  sm[t] = v;
  __syncthreads();
  for (int o = 1; o < 512; o <<= 1) {
    int x = (t >= o) ? sm[t - o] : 0;
    __syncthreads();
    sm[t] += x;
    __syncthreads();
  }
  if (t < NB) { int e = sm[t] - v; bbase[t] = e; gcur[t] = e; }
  if (t == 511) { bbase[NB] = sm[511]; offs[N] = sm[511]; }
}

// ---------------- bucket partition (write-combining friendly) ----------------
__global__ __launch_bounds__(256) void k_bucket(const int* __restrict__ ei,
                                                const int* __restrict__ wghist,
                                                int* __restrict__ gcur,
                                                int2* __restrict__ bpairs, int E, int NB) {
  __shared__ int lbase[NBMAX];
  __shared__ int lcur[NBMAX];
  for (int t = threadIdx.x; t < NB; t += 256) {
    int c = wghist[blockIdx.x * NBMAX + t];
    lbase[t] = c ? atomicAdd(&gcur[t], c) : 0;
    lcur[t] = 0;
  }
  __syncthreads();
  int base = blockIdx.x * CHUNK;
#pragma unroll
  for (int i = 0; i < CHUNK / 256; ++i) {
    int e = base + i * 256 + threadIdx.x;
    if (e < E) {
      int s = ei[e], d = ei[E + e];
      int b = d >> 8;
      int p = lbase[b] + atomicAdd(&lcur[b], 1);
      bpairs[p] = make_int2(s, d);
    }
  }
}

// ---------------- per-bucket CSR + offs + nrm ----------------
__global__ __launch_bounds__(256) void k_csr(const int2* __restrict__ bpairs,
                                             const int* __restrict__ bbase,
                                             int* __restrict__ offs, float* __restrict__ nrm,
                                             int* __restrict__ csr_src, int N) {
  __shared__ int hist[256];
  __shared__ int scan[256];
  __shared__ int cur[256];
  const int t = threadIdx.x;
  const int b = blockIdx.x;
  const int d0 = b << 8;
  const int nn = min(256, N - d0);
  const int base = bbase[b], end = bbase[b + 1];
  hist[t] = 0;
  __syncthreads();
  for (int e = base + t; e < end; e += 256) atomicAdd(&hist[bpairs[e].y - d0], 1);
  __syncthreads();
  int myc = hist[t];
  scan[t] = myc;
  __syncthreads();
  for (int o = 1; o < 256; o <<= 1) {
    int x = (t >= o) ? scan[t - o] : 0;
    __syncthreads();
    scan[t] += x;
    __syncthreads();
  }
  int excl = scan[t] - myc;
  if (t < nn) {
    offs[d0 + t] = base + excl;
    nrm[d0 + t] = rsqrtf(fmaxf((float)myc, 1.f));
  }
  cur[t] = excl;
  __syncthreads();
  for (int e = base + t; e < end; e += 256) {
    int2 pr = bpairs[e];
    int pos = atomicAdd(&cur[pr.y - d0], 1);
    csr_src[base + pos] = pr.x;
  }
}

// ---------------- weight pre-transpose (bf16) ----------------
// Wt[j][k] = [W1|Wy]^T, j<192, k<512.  grid 512 (k), block 192 (j).
__global__ void k_wprep(const float* __restrict__ W1, const float* __restrict__ Wy,
                        unsigned short* __restrict__ Wt) {
  int k = blockIdx.x, j = threadIdx.x;
  float v = (j < 128) ? W1[k * 128 + j] : Wy[k * 64 + (j - 128)];
  Wt[j * 512 + k] = f2bf(v);
}
// Wt2[j][k] = W2^T, j<64, k<128.  grid 128 (k), block 64 (j).
__global__ void k_wprep2(const float* __restrict__ W2, unsigned short* __restrict__ Wt2) {
  int k = blockIdx.x, j = threadIdx.x;
  Wt2[j * 128 + k] = f2bf(W2[k * 64 + j]);
}

// ---------------- fused dense front-end (128-node tile) ----------------
// C = X @ [W1|Wy] via bf16 MFMA (swapped operands: A=W^T, B=X^T), then
// h=relu(.+b1) -> Hs, logits=softmax(.), h0 = h@W2 + b2; outputs the packed
// norm-prescaled state pk0 and h0 in bf16.
__global__ __launch_bounds__(256) void k_transform(
    const unsigned short* __restrict__ Wt, const unsigned short* __restrict__ Wt2,
    const float* __restrict__ X, const float* __restrict__ b1, const float* __restrict__ b2,
    const float* __restrict__ nrm,
    unsigned int* __restrict__ pk0, unsigned short* __restrict__ h0b, int n)
{
  __shared__ short Xs[128 * 32];   // [m][k]  rowbytes 64
  __shared__ short Ws[192 * 32];   // [j][k]  rowbytes 64
  __shared__ short Hs[128 * 128];  // [m][j]  rowbytes 256
  __shared__ short W2s[64 * 128];  // [j2][k2] rowbytes 256

  const int tid = threadIdx.x;
  const int w = tid >> 6;
  const int lane = tid & 63;
  const int c = lane & 15;
  const int g = lane >> 4;
  const int m0 = blockIdx.x * 128;

  // stage W2^T once: 64 rows x 128 shorts = 1024 chunks of 8 (16 chunks/row)
#pragma unroll
  for (int i = 0; i < 4; ++i) {
    int cc = tid + i * 256;
    int j2 = cc >> 4, k8 = (cc & 15) * 8;
    bf16x8 v = *(const bf16x8*)&Wt2[j2 * 128 + k8];
    *(bf16x8*)ldsp(W2s, j2, 256, k8) = v;
  }

  f32x4 zero4 = {0.f, 0.f, 0.f, 0.f};
  f32x4 acc[2][12];
#pragma unroll
  for (int mi = 0; mi < 2; ++mi)
#pragma unroll
    for (int i = 0; i < 12; ++i) acc[mi][i] = zero4;

  const int xr = tid >> 1;
  const int xc = (tid & 1) * 16;
  const int xrow = m0 + xr;

  for (int kk = 0; kk < 512; kk += 32) {
    // X stage: 16 f32 per thread -> 2 ds_write_b128
    float4 f[4];
    if (xrow < n) {
      const float4* p = (const float4*)(X + (size_t)xrow * 512 + kk + xc);
      f[0] = p[0]; f[1] = p[1]; f[2] = p[2]; f[3] = p[3];
    } else {
      float4 z = {0.f, 0.f, 0.f, 0.f};
      f[0] = z; f[1] = z; f[2] = z; f[3] = z;
    }
    bf16x8 lo, hi;
    {
      const float* fp = (const float*)f;
#pragma unroll
      for (int q = 0; q < 8; ++q) { lo[q] = (short)f2bf(fp[q]); hi[q] = (short)f2bf(fp[8 + q]); }
    }
    *(bf16x8*)ldsp(Xs, xr, 64, xc) = lo;
    *(bf16x8*)ldsp(Xs, xr, 64, xc + 8) = hi;
    // W stage: 192 rows x 32 shorts = 768 chunks of 8 (4 chunks/row)
#pragma unroll
    for (int i = 0; i < 3; ++i) {
      int cc = tid + i * 256;
      int j = cc >> 2, k8 = (cc & 3) * 8;
      bf16x8 v = *(const bf16x8*)&Wt[j * 512 + kk + k8];
      *(bf16x8*)ldsp(Ws, j, 64, k8) = v;
    }
    __syncthreads();
    bf16x8 bx0 = *(const bf16x8*)ldsp(Xs, w * 32 + c, 64, g * 8);
    bf16x8 bx1 = *(const bf16x8*)ldsp(Xs, w * 32 + 16 + c, 64, g * 8);
#pragma unroll
    for (int jt = 0; jt < 12; ++jt) {
      bf16x8 aw = *(const bf16x8*)ldsp(Ws, jt * 16 + c, 64, g * 8);
      acc[0][jt] = __builtin_amdgcn_mfma_f32_16x16x32_bf16(aw, bx0, acc[0][jt], 0, 0, 0);
      acc[1][jt] = __builtin_amdgcn_mfma_f32_16x16x32_bf16(aw, bx1, acc[1][jt], 0, 0, 0);
    }
    __syncthreads();
  }

  // epilogue phase 1: h -> Hs (bf16), softmax in registers
  float lv[2][16];
  float inv_[2];
#pragma unroll
  for (int mi = 0; mi < 2; ++mi) {
    int m = w * 32 + mi * 16 + c;
#pragma unroll
    for (int jt = 0; jt < 8; ++jt) {
      int jb = jt * 16 + g * 4;
      bf16x4 hv;
#pragma unroll
      for (int q = 0; q < 4; ++q) {
        float hvf = fmaxf(acc[mi][jt][q] + b1[jb + q], 0.f);
        hv[q] = (short)f2bf(hvf);
      }
      *(bf16x4*)ldsp(Hs, m, 256, jb) = hv;
    }
    float mx = -3.4e38f;
#pragma unroll
    for (int t = 0; t < 4; ++t)
#pragma unroll
      for (int q = 0; q < 4; ++q) {
        float vv = acc[mi][8 + t][q];
        lv[mi][t * 4 + q] = vv;
        mx = fmaxf(mx, vv);
      }
    mx = fmaxf(mx, __shfl_xor(mx, 16, 64));
    mx = fmaxf(mx, __shfl_xor(mx, 32, 64));
    float sum = 0.f;
#pragma unroll
    for (int i = 0; i < 16; ++i) { lv[mi][i] = __expf(lv[mi][i] - mx); sum += lv[mi][i]; }
    sum += __shfl_xor(sum, 16, 64);
    sum += __shfl_xor(sum, 32, 64);
    inv_[mi] = 1.f / sum;
  }
  __syncthreads();

  // epilogue phase 2: h0 = Hs @ W2 (K=128)
  f32x4 acc2[2][4];
#pragma unroll
  for (int mi = 0; mi < 2; ++mi)
#pragma unroll
    for (int i = 0; i < 4; ++i) acc2[mi][i] = zero4;
#pragma unroll
  for (int kk2 = 0; kk2 < 4; ++kk2) {
    bf16x8 bh0 = *(const bf16x8*)ldsp(Hs, w * 32 + c, 256, kk2 * 32 + g * 8);
    bf16x8 bh1 = *(const bf16x8*)ldsp(Hs, w * 32 + 16 + c, 256, kk2 * 32 + g * 8);
#pragma unroll
    for (int j2t = 0; j2t < 4; ++j2t) {
      bf16x8 a2 = *(const bf16x8*)ldsp(W2s, j2t * 16 + c, 256, kk2 * 32 + g * 8);
      acc2[0][j2t] = __builtin_amdgcn_mfma_f32_16x16x32_bf16(a2, bh0, acc2[0][j2t], 0, 0, 0);
      acc2[1][j2t] = __builtin_amdgcn_mfma_f32_16x16x32_bf16(a2, bh1, acc2[1][j2t], 0, 0, 0);
    }
  }

#pragma unroll
  for (int mi = 0; mi < 2; ++mi) {
    int m = w * 32 + mi * 16 + c;
    int grow = m0 + m;
    if (grow < n) {
      float nd = nrm[grow];
#pragma unroll
      for (int t = 0; t < 4; ++t) {
        int cb = t * 16 + g * 4;
        u32x4 pkv;
        bf16x4 hb;
#pragma unroll
        for (int q = 0; q < 4; ++q) {
          float lg  = lv[mi][t * 4 + q] * inv_[mi];
          float h0v = acc2[mi][t][q] + b2[cb + q];
          hb[q]  = (short)f2bf(h0v);
          pkv[q] = ((unsigned)f2bf(nd * h0v) << 16) | (unsigned)f2bf(nd * lg);
        }
        *(u32x4*)(pk0 + (size_t)grow * 64 + cb) = pkv;
        *(bf16x4*)(h0b + (size_t)grow * 64 + cb) = hb;
      }
    }
  }
}

// ---------------- fused gated propagation step ----------------
__global__ __launch_bounds__(256) void k_prop(
    const int* __restrict__ offs, const int* __restrict__ csr_src,
    const unsigned int* __restrict__ pk_in, unsigned int* __restrict__ pk_out,
    const unsigned short* __restrict__ h0b, const float* __restrict__ nrm,
    float* __restrict__ final_out, int n, int last)
{
  const int lane = threadIdx.x & 63;
  const int node = blockIdx.x * 4 + (threadIdx.x >> 6);
  if (node >= n) return;
  const int beg = offs[node], end = offs[node + 1];

  float aL0 = 0.f, aL1 = 0.f, aH0 = 0.f, aH1 = 0.f;
  int e = beg;
  for (; e + 8 <= end; e += 8) {
    int s0 = csr_src[e + 0], s1 = csr_src[e + 1], s2 = csr_src[e + 2], s3 = csr_src[e + 3];
    int s4 = csr_src[e + 4], s5 = csr_src[e + 5], s6 = csr_src[e + 6], s7 = csr_src[e + 7];
    unsigned w0 = pk_in[(size_t)s0 * 64 + lane];
    unsigned w1 = pk_in[(size_t)s1 * 64 + lane];
    unsigned w2 = pk_in[(size_t)s2 * 64 + lane];
    unsigned w3 = pk_in[(size_t)s3 * 64 + lane];
    unsigned w4 = pk_in[(size_t)s4 * 64 + lane];
    unsigned w5 = pk_in[(size_t)s5 * 64 + lane];
    unsigned w6 = pk_in[(size_t)s6 * 64 + lane];
    unsigned w7 = pk_in[(size_t)s7 * 64 + lane];
    aL0 += bflo(w0) + bflo(w1) + bflo(w2) + bflo(w3);
    aL1 += bflo(w4) + bflo(w5) + bflo(w6) + bflo(w7);
    aH0 += bfhi(w0) + bfhi(w1) + bfhi(w2) + bfhi(w3);
    aH1 += bfhi(w4) + bfhi(w5) + bfhi(w6) + bfhi(w7);
  }
  for (; e < end; ++e) {
    unsigned w = pk_in[(size_t)csr_src[e] * 64 + lane];
    aL0 += bflo(w);
    aH0 += bfhi(w);
  }
  float aL = aL0 + aL1;
  float aH = aH0 + aH1;

  size_t base = (size_t)node * 64 + lane;
  float p = bflo(pk_in[base]) * aL;   // nrm[d] cancels in the gate
#pragma unroll
  for (int off = 32; off >= 1; off >>= 1) p += __shfl_xor(p, off, 64);
  float z = 1.f / (1.f + __expf(-p));

  float nd = nrm[node];
  float h0v = __uint_as_float((unsigned)h0b[base] << 16);
  float hn = z * nd * aH + (1.f - z) * h0v;

  if (last) {
    final_out[base] = hn;
  } else {
    pk_out[base] = ((unsigned)f2bf(nd * hn) << 16) | (unsigned)f2bf(nd * nd * aL);
  }
}

// ---------------- launch ----------------
extern "C" void kernel_launch(void* const* d_in, const int* in_sizes, int n_in,
                              void* d_out, int out_size, void* d_ws, size_t ws_size,
                              hipStream_t stream) {
  (void)n_in; (void)out_size; (void)ws_size;
  const float* X  = (const float*)d_in[0];
  const float* W1 = (const float*)d_in[1];
  const float* b1 = (const float*)d_in[2];
  const float* W2 = (const float*)d_in[3];
  const float* b2 = (const float*)d_in[4];
  const float* Wy = (const float*)d_in[5];
  const int*   ei = (const int*)d_in[6];
  const int N = in_sizes[0] / 512;
  const int E = in_sizes[6] / 2;
  const int NB = (N + 255) >> 8;            // nodes-per-bucket = 256
  const int NWG = (E + CHUNK - 1) / CHUNK;

  char* p = (char*)d_ws;
  auto alloc = [&](size_t bytes) -> char* {
    char* r = p; p += (bytes + 255) & ~(size_t)255; return r;
  };
  int*            gcnt    = (int*)  alloc(NBMAX * 4);
  int*            bbase   = (int*)  alloc((NBMAX + 1) * 4);
  int*            gcur    = (int*)  alloc(NBMAX * 4);
  int*            wghist  = (int*)  alloc((size_t)NWG * NBMAX * 4);
  int*            offs    = (int*)  alloc((size_t)(N + 1) * 4);
  float*          nrm     = (float*)alloc((size_t)N * 4);
  int*            csr_src = (int*)  alloc((size_t)E * 4);
  unsigned short* Wt      = (unsigned short*)alloc(192 * 512 * 2);
  unsigned short* Wt2     = (unsigned short*)alloc(64 * 128 * 2);
  size_t pkbytes = (size_t)N * 64 * 4;
  size_t bpbytes = (size_t)E * 8;
  char*           shared0 = alloc(pkbytes > bpbytes ? pkbytes : bpbytes);
  int2*           bpairs  = (int2*)shared0;          // dead after k_csr
  unsigned int*   pkA     = (unsigned int*)shared0;  // alias: born at k_transform
  unsigned int*   pkB     = (unsigned int*)alloc(pkbytes);
  unsigned short* h0b     = (unsigned short*)alloc((size_t)N * 64 * 2);

  hipMemsetAsync(gcnt, 0, NBMAX * 4, stream);

  k_wprep<<<512, 192, 0, stream>>>(W1, Wy, Wt);
  k_wprep2<<<128, 64, 0, stream>>>(W2, Wt2);
  k_bhist<<<NWG, 256, 0, stream>>>(ei, E, NB, gcnt, wghist);
  k_bscan<<<1, 512, 0, stream>>>(gcnt, bbase, gcur, offs, NB, N);
  k_bucket<<<NWG, 256, 0, stream>>>(ei, wghist, gcur, bpairs, E, NB);
  k_csr<<<NB, 256, 0, stream>>>(bpairs, bbase, offs, nrm, csr_src, N);
  k_transform<<<(N + 127) / 128, 256, 0, stream>>>(Wt, Wt2, X, b1, b2, nrm, pkA, h0b, N);

  for (int k = 0; k < 10; ++k) {
    const unsigned int* in  = (k & 1) ? pkB : pkA;
    unsigned int*       out = (k & 1) ? pkA : pkB;
    k_prop<<<(N + 3) / 4, 256, 0, stream>>>(offs, csr_src, in, out, h0b, nrm,
                                            (float*)d_out, N, (k == 9) ? 1 : 0);
  }
}

// Round 5
// 1333.823 us; speedup vs baseline: 2.6902x; 1.0053x over previous
//
#include <hip/hip_runtime.h>

typedef __attribute__((ext_vector_type(8))) short bf16x8;
typedef __attribute__((ext_vector_type(4))) short bf16x4;
typedef __attribute__((ext_vector_type(4))) float f32x4;
typedef __attribute__((ext_vector_type(4))) unsigned int u32x4;

__device__ __forceinline__ unsigned short f2bf(float f) {
  unsigned int u = __float_as_uint(f);
  u += 0x7fffu + ((u >> 16) & 1u);   // RNE
  return (unsigned short)(u >> 16);
}
__device__ __forceinline__ float bflo(unsigned int w) { return __uint_as_float(w << 16); }
__device__ __forceinline__ float bfhi(unsigned int w) { return __uint_as_float(w & 0xffff0000u); }

// Swizzled LDS address: dense row stride + XOR((row&7)<<4) -> <=2-way conflicts.
__device__ __forceinline__ short* ldsp(short* base, int row, int rowbytes, int colshort) {
  int off = row * rowbytes + colshort * 2;
  off ^= ((row & 7) << 4);
  return (short*)((char*)base + off);
}

#define CHUNK 8192
#define NBMAX 512

// ---------------- CSR build: bucket histogram ----------------
__global__ __launch_bounds__(256) void k_bhist(const int* __restrict__ ei, int E, int NB,
                                               int* __restrict__ gcnt, int* __restrict__ wghist) {
  __shared__ int h[NBMAX];
  for (int t = threadIdx.x; t < NB; t += 256) h[t] = 0;
  __syncthreads();
  int base = blockIdx.x * CHUNK;
#pragma unroll
  for (int i = 0; i < CHUNK / 256; ++i) {
    int e = base + i * 256 + threadIdx.x;
    if (e < E) atomicAdd(&h[ei[E + e] >> 8], 1);
  }
  __syncthreads();
  for (int t = threadIdx.x; t < NB; t += 256) {
    int c = h[t];
    wghist[blockIdx.x * NBMAX + t] = c;
    if (c) atomicAdd(&gcnt[t], c);
  }
}

// ---------------- bucket-count scan ----------------
__global__ void k_bscan(const int* __restrict__ gcnt, int* __restrict__ bbase,
                        int* __restrict__ gcur, int* __restrict__ offs, int NB, int N) {
  __shared__ int sm[512];
  int t = threadIdx.x;
  int v = (t < NB) ? gcnt[t] : 0;
  sm[t] = v;
  __syncthreads();
  for (int o = 1; o < 512; o <<= 1) {
    int x = (t >= o) ? sm[t - o] : 0;
    __syncthreads();
    sm[t] += x;
    __syncthreads();
  }
  if (t < NB) { int e = sm[t] - v; bbase[t] = e; gcur[t] = e; }
  if (t == 511) { bbase[NB] = sm[511]; offs[N] = sm[511]; }
}

// ---------------- bucket partition (write-combining friendly) ----------------
__global__ __launch_bounds__(256) void k_bucket(const int* __restrict__ ei,
                                                const int* __restrict__ wghist,
                                                int* __restrict__ gcur,
                                                int2* __restrict__ bpairs, int E, int NB) {
  __shared__ int lbase[NBMAX];
  __shared__ int lcur[NBMAX];
  for (int t = threadIdx.x; t < NB; t += 256) {
    int c = wghist[blockIdx.x * NBMAX + t];
    lbase[t] = c ? atomicAdd(&gcur[t], c) : 0;
    lcur[t] = 0;
  }
  __syncthreads();
  int base = blockIdx.x * CHUNK;
#pragma unroll
  for (int i = 0; i < CHUNK / 256; ++i) {
    int e = base + i * 256 + threadIdx.x;
    if (e < E) {
      int s = ei[e], d = ei[E + e];
      int b = d >> 8;
      int p = lbase[b] + atomicAdd(&lcur[b], 1);
      bpairs[p] = make_int2(s, d);
    }
  }
}

// ---------------- per-bucket CSR + offs + nrm + group widths ----------------
__global__ __launch_bounds__(256) void k_csr(const int2* __restrict__ bpairs,
                                             const int* __restrict__ bbase,
                                             int* __restrict__ offs, float* __restrict__ nrm,
                                             int* __restrict__ csr_src,
                                             int* __restrict__ gslots, int N) {
  __shared__ int hist[256];
  __shared__ int scan[256];
  __shared__ int cur[256];
  const int t = threadIdx.x;
  const int b = blockIdx.x;
  const int d0 = b << 8;
  const int nn = min(256, N - d0);
  const int base = bbase[b], end = bbase[b + 1];
  hist[t] = 0;
  __syncthreads();
  for (int e = base + t; e < end; e += 256) atomicAdd(&hist[bpairs[e].y - d0], 1);
  __syncthreads();
  int myc = hist[t];
  scan[t] = myc;
  __syncthreads();
  for (int o = 1; o < 256; o <<= 1) {
    int x = (t >= o) ? scan[t - o] : 0;
    __syncthreads();
    scan[t] += x;
    __syncthreads();
  }
  int excl = scan[t] - myc;
  if (t < nn) {
    offs[d0 + t] = base + excl;
    nrm[d0 + t] = rsqrtf(fmaxf((float)myc, 1.f));
  }
  if (t < 64) {  // group width: 4 nodes per group, 64 groups per bucket
    int w0 = hist[4 * t + 0], w1 = hist[4 * t + 1];
    int w2 = hist[4 * t + 2], w3 = hist[4 * t + 3];
    gslots[b * 64 + t] = 4 * max(max(w0, w1), max(w2, w3));
  }
  cur[t] = excl;
  __syncthreads();
  for (int e = base + t; e < end; e += 256) {
    int2 pr = bpairs[e];
    int pos = atomicAdd(&cur[pr.y - d0], 1);
    csr_src[base + pos] = pr.x;
  }
}

// ---------------- hierarchical exclusive scan (for group offsets) ----------------
__global__ void k_scan1(const int* __restrict__ in, int* __restrict__ out,
                        int* __restrict__ bsum, int n) {
  __shared__ int sm[1024];
  int t = threadIdx.x;
  int gid = blockIdx.x * 1024 + t;
  int v = (gid < n) ? in[gid] : 0;
  sm[t] = v;
  __syncthreads();
  for (int off = 1; off < 1024; off <<= 1) {
    int x = (t >= off) ? sm[t - off] : 0;
    __syncthreads();
    sm[t] += x;
    __syncthreads();
  }
  if (gid < n) out[gid] = sm[t] - v;
  if (t == 1023) bsum[blockIdx.x] = sm[1023];
}

__global__ void k_scan2(int* __restrict__ bsum, int nb) {
  __shared__ int sm[128];
  int t = threadIdx.x;
  int v = (t < nb) ? bsum[t] : 0;
  sm[t] = v;
  __syncthreads();
  for (int o = 1; o < 128; o <<= 1) {
    int x = (t >= o) ? sm[t - o] : 0;
    __syncthreads();
    sm[t] += x;
    __syncthreads();
  }
  if (t < nb) bsum[t] = sm[t] - v;
  if (t == 127) bsum[nb] = sm[127];
}

__global__ void k_scan3(int* __restrict__ out, const int* __restrict__ bsum, int n) {
  int gid = blockIdx.x * 1024 + threadIdx.x;
  if (gid < n) out[gid] += bsum[blockIdx.x];
  if (gid == 0) out[n] = bsum[gridDim.x];
}

// ---------------- ELL fill: padded per-group edge slots (byte offsets) ----------------
// Slot layout per group g: for iteration i, sub-node s: pidx[gof[g]+i*4+s].
// Padded slots point at the all-zero row N. Also zeroes row N of both pk buffers.
__global__ __launch_bounds__(64) void k_ell(
    const int* __restrict__ offs, const int* __restrict__ csr_src,
    const int* __restrict__ gof, unsigned* __restrict__ pidx,
    unsigned int* __restrict__ pkA, unsigned int* __restrict__ pkB, int N) {
  int g = blockIdx.x;
  int t = threadIdx.x;
  if (g == 0) {   // zero padding row
    pkA[(size_t)N * 64 + t] = 0;
    pkB[(size_t)N * 64 + t] = 0;
  }
  int base = gof[g];
  int slots = gof[g + 1] - base;
  int o[4], d[4];
#pragma unroll
  for (int s = 0; s < 4; ++s) {
    int nd_ = g * 4 + s;
    o[s] = (nd_ < N) ? offs[nd_] : 0;
    d[s] = (nd_ < N) ? (offs[nd_ + 1] - o[s]) : 0;
  }
  unsigned zoff = (unsigned)N << 8;
  for (int j = t; j < slots; j += 64) {
    int i = j >> 2, s = j & 3;
    pidx[base + j] = (i < d[s]) ? ((unsigned)csr_src[o[s] + i] << 8) : zoff;
  }
}

// ---------------- weight pre-transpose (bf16) ----------------
__global__ void k_wprep(const float* __restrict__ W1, const float* __restrict__ Wy,
                        unsigned short* __restrict__ Wt) {
  int k = blockIdx.x, j = threadIdx.x;
  float v = (j < 128) ? W1[k * 128 + j] : Wy[k * 64 + (j - 128)];
  Wt[j * 512 + k] = f2bf(v);
}
__global__ void k_wprep2(const float* __restrict__ W2, unsigned short* __restrict__ Wt2) {
  int k = blockIdx.x, j = threadIdx.x;
  Wt2[j * 128 + k] = f2bf(W2[k * 64 + j]);
}

// ---------------- fused dense front-end (128-node tile) ----------------
__global__ __launch_bounds__(256) void k_transform(
    const unsigned short* __restrict__ Wt, const unsigned short* __restrict__ Wt2,
    const float* __restrict__ X, const float* __restrict__ b1, const float* __restrict__ b2,
    const float* __restrict__ nrm,
    unsigned int* __restrict__ pk0, unsigned short* __restrict__ h0b, int n)
{
  __shared__ short Xs[128 * 32];   // [m][k]  rowbytes 64
  __shared__ short Ws[192 * 32];   // [j][k]  rowbytes 64
  __shared__ short Hs[128 * 128];  // [m][j]  rowbytes 256
  __shared__ short W2s[64 * 128];  // [j2][k2] rowbytes 256

  const int tid = threadIdx.x;
  const int w = tid >> 6;
  const int lane = tid & 63;
  const int c = lane & 15;
  const int g = lane >> 4;
  const int m0 = blockIdx.x * 128;

  // stage W2^T once: 64 rows x 128 shorts = 1024 chunks of 8 (16 chunks/row)
#pragma unroll
  for (int i = 0; i < 4; ++i) {
    int cc = tid + i * 256;
    int j2 = cc >> 4, k8 = (cc & 15) * 8;
    bf16x8 v = *(const bf16x8*)&Wt2[j2 * 128 + k8];
    *(bf16x8*)ldsp(W2s, j2, 256, k8) = v;
  }

  f32x4 zero4 = {0.f, 0.f, 0.f, 0.f};
  f32x4 acc[2][12];
#pragma unroll
  for (int mi = 0; mi < 2; ++mi)
#pragma unroll
    for (int i = 0; i < 12; ++i) acc[mi][i] = zero4;

  const int xr = tid >> 1;
  const int xc = (tid & 1) * 16;
  const int xrow = m0 + xr;

  for (int kk = 0; kk < 512; kk += 32) {
    float4 f[4];
    if (xrow < n) {
      const float4* p = (const float4*)(X + (size_t)xrow * 512 + kk + xc);
      f[0] = p[0]; f[1] = p[1]; f[2] = p[2]; f[3] = p[3];
    } else {
      float4 z = {0.f, 0.f, 0.f, 0.f};
      f[0] = z; f[1] = z; f[2] = z; f[3] = z;
    }
    bf16x8 lo, hi;
    {
      const float* fp = (const float*)f;
#pragma unroll
      for (int q = 0; q < 8; ++q) { lo[q] = (short)f2bf(fp[q]); hi[q] = (short)f2bf(fp[8 + q]); }
    }
    *(bf16x8*)ldsp(Xs, xr, 64, xc) = lo;
    *(bf16x8*)ldsp(Xs, xr, 64, xc + 8) = hi;
#pragma unroll
    for (int i = 0; i < 3; ++i) {
      int cc = tid + i * 256;
      int j = cc >> 2, k8 = (cc & 3) * 8;
      bf16x8 v = *(const bf16x8*)&Wt[j * 512 + kk + k8];
      *(bf16x8*)ldsp(Ws, j, 64, k8) = v;
    }
    __syncthreads();
    bf16x8 bx0 = *(const bf16x8*)ldsp(Xs, w * 32 + c, 64, g * 8);
    bf16x8 bx1 = *(const bf16x8*)ldsp(Xs, w * 32 + 16 + c, 64, g * 8);
#pragma unroll
    for (int jt = 0; jt < 12; ++jt) {
      bf16x8 aw = *(const bf16x8*)ldsp(Ws, jt * 16 + c, 64, g * 8);
      acc[0][jt] = __builtin_amdgcn_mfma_f32_16x16x32_bf16(aw, bx0, acc[0][jt], 0, 0, 0);
      acc[1][jt] = __builtin_amdgcn_mfma_f32_16x16x32_bf16(aw, bx1, acc[1][jt], 0, 0, 0);
    }
    __syncthreads();
  }

  float lv[2][16];
  float inv_[2];
#pragma unroll
  for (int mi = 0; mi < 2; ++mi) {
    int m = w * 32 + mi * 16 + c;
#pragma unroll
    for (int jt = 0; jt < 8; ++jt) {
      int jb = jt * 16 + g * 4;
      bf16x4 hv;
#pragma unroll
      for (int q = 0; q < 4; ++q) {
        float hvf = fmaxf(acc[mi][jt][q] + b1[jb + q], 0.f);
        hv[q] = (short)f2bf(hvf);
      }
      *(bf16x4*)ldsp(Hs, m, 256, jb) = hv;
    }
    float mx = -3.4e38f;
#pragma unroll
    for (int t = 0; t < 4; ++t)
#pragma unroll
      for (int q = 0; q < 4; ++q) {
        float vv = acc[mi][8 + t][q];
        lv[mi][t * 4 + q] = vv;
        mx = fmaxf(mx, vv);
      }
    mx = fmaxf(mx, __shfl_xor(mx, 16, 64));
    mx = fmaxf(mx, __shfl_xor(mx, 32, 64));
    float sum = 0.f;
#pragma unroll
    for (int i = 0; i < 16; ++i) { lv[mi][i] = __expf(lv[mi][i] - mx); sum += lv[mi][i]; }
    sum += __shfl_xor(sum, 16, 64);
    sum += __shfl_xor(sum, 32, 64);
    inv_[mi] = 1.f / sum;
  }
  __syncthreads();

  f32x4 acc2[2][4];
#pragma unroll
  for (int mi = 0; mi < 2; ++mi)
#pragma unroll
    for (int i = 0; i < 4; ++i) acc2[mi][i] = zero4;
#pragma unroll
  for (int kk2 = 0; kk2 < 4; ++kk2) {
    bf16x8 bh0 = *(const bf16x8*)ldsp(Hs, w * 32 + c, 256, kk2 * 32 + g * 8);
    bf16x8 bh1 = *(const bf16x8*)ldsp(Hs, w * 32 + 16 + c, 256, kk2 * 32 + g * 8);
#pragma unroll
    for (int j2t = 0; j2t < 4; ++j2t) {
      bf16x8 a2 = *(const bf16x8*)ldsp(W2s, j2t * 16 + c, 256, kk2 * 32 + g * 8);
      acc2[0][j2t] = __builtin_amdgcn_mfma_f32_16x16x32_bf16(a2, bh0, acc2[0][j2t], 0, 0, 0);
      acc2[1][j2t] = __builtin_amdgcn_mfma_f32_16x16x32_bf16(a2, bh1, acc2[1][j2t], 0, 0, 0);
    }
  }

#pragma unroll
  for (int mi = 0; mi < 2; ++mi) {
    int m = w * 32 + mi * 16 + c;
    int grow = m0 + m;
    if (grow < n) {
      float nd = nrm[grow];
#pragma unroll
      for (int t = 0; t < 4; ++t) {
        int cb = t * 16 + g * 4;
        u32x4 pkv;
        bf16x4 hb;
#pragma unroll
        for (int q = 0; q < 4; ++q) {
          float lg  = lv[mi][t * 4 + q] * inv_[mi];
          float h0v = acc2[mi][t][q] + b2[cb + q];
          hb[q]  = (short)f2bf(h0v);
          pkv[q] = ((unsigned)f2bf(nd * h0v) << 16) | (unsigned)f2bf(nd * lg);
        }
        *(u32x4*)(pk0 + (size_t)grow * 64 + cb) = pkv;
        *(bf16x4*)(h0b + (size_t)grow * 64 + cb) = hb;
      }
    }
  }
}

// ---------------- fused gated propagation step (ELL, 4 nodes/wave) ----------------
// 16 lanes per node (lane&15 = class quad, uint4 = 4 packed classes).
// Padded slots hit the all-zero row N: no divergence, no tails.
__global__ __launch_bounds__(256) void k_prop(
    const int* __restrict__ gof, const unsigned* __restrict__ pidx,
    const unsigned int* __restrict__ pk_in, unsigned int* __restrict__ pk_out,
    const unsigned short* __restrict__ h0b, const float* __restrict__ nrm,
    float* __restrict__ final_out, int n, int ng, int last)
{
  const int lane = threadIdx.x & 63;
  const int g = blockIdx.x * 4 + (threadIdx.x >> 6);
  if (g >= ng) return;
  const int sub = lane >> 4;
  const int cq  = lane & 15;
  const int node = g * 4 + sub;
  const int beg = gof[g];
  const int w = (gof[g + 1] - beg) >> 2;
  const char* pkc = (const char*)pk_in;
  const unsigned* ib = pidx + beg + sub;
  const int coff = cq << 4;

  float aL[4] = {0.f, 0.f, 0.f, 0.f}, aH[4] = {0.f, 0.f, 0.f, 0.f};
  float bL[4] = {0.f, 0.f, 0.f, 0.f}, bH[4] = {0.f, 0.f, 0.f, 0.f};
  int i = 0;
  for (; i + 2 <= w; i += 2) {
    unsigned r0 = ib[4 * i];
    unsigned r1 = ib[4 * i + 4];
    u32x4 w0 = *(const u32x4*)(pkc + r0 + coff);
    u32x4 w1 = *(const u32x4*)(pkc + r1 + coff);
#pragma unroll
    for (int q = 0; q < 4; ++q) {
      aL[q] += bflo(w0[q]); aH[q] += bfhi(w0[q]);
      bL[q] += bflo(w1[q]); bH[q] += bfhi(w1[q]);
    }
  }
  if (i < w) {
    unsigned r0 = ib[4 * i];
    u32x4 w0 = *(const u32x4*)(pkc + r0 + coff);
#pragma unroll
    for (int q = 0; q < 4; ++q) { aL[q] += bflo(w0[q]); aH[q] += bfhi(w0[q]); }
  }
#pragma unroll
  for (int q = 0; q < 4; ++q) { aL[q] += bL[q]; aH[q] += bH[q]; }

  if (node >= n) return;
  // gate: sum over all 64 classes of L_d[c]*aL[c] (nrm[d] cancels)
  u32x4 own = *(const u32x4*)(pkc + (node << 8) + coff);
  float p = 0.f;
#pragma unroll
  for (int q = 0; q < 4; ++q) p += bflo(own[q]) * aL[q];
  p += __shfl_xor(p, 1, 64);
  p += __shfl_xor(p, 2, 64);
  p += __shfl_xor(p, 4, 64);
  p += __shfl_xor(p, 8, 64);
  float z = 1.f / (1.f + __expf(-p));
  float nd = nrm[node];
  bf16x4 h0v = *(const bf16x4*)(h0b + (size_t)node * 64 + cq * 4);

  if (last) {
    float4 o;
    float* op = &o.x;
#pragma unroll
    for (int q = 0; q < 4; ++q) {
      float h0f = __uint_as_float(((unsigned)(unsigned short)h0v[q]) << 16);
      op[q] = z * nd * aH[q] + (1.f - z) * h0f;
    }
    *(float4*)(final_out + (size_t)node * 64 + cq * 4) = o;
  } else {
    u32x4 pkv;
    float nn2 = nd * nd;
#pragma unroll
    for (int q = 0; q < 4; ++q) {
      float h0f = __uint_as_float(((unsigned)(unsigned short)h0v[q]) << 16);
      float hn = z * nd * aH[q] + (1.f - z) * h0f;
      pkv[q] = ((unsigned)f2bf(nd * hn) << 16) | (unsigned)f2bf(nn2 * aL[q]);
    }
    *(u32x4*)((char*)pk_out + (node << 8) + coff) = pkv;
  }
}

// ---------------- launch ----------------
extern "C" void kernel_launch(void* const* d_in, const int* in_sizes, int n_in,
                              void* d_out, int out_size, void* d_ws, size_t ws_size,
                              hipStream_t stream) {
  (void)n_in; (void)out_size; (void)ws_size;
  const float* X  = (const float*)d_in[0];
  const float* W1 = (const float*)d_in[1];
  const float* b1 = (const float*)d_in[2];
  const float* W2 = (const float*)d_in[3];
  const float* b2 = (const float*)d_in[4];
  const float* Wy = (const float*)d_in[5];
  const int*   ei = (const int*)d_in[6];
  const int N = in_sizes[0] / 512;
  const int E = in_sizes[6] / 2;
  const int NB = (N + 255) >> 8;            // nodes-per-bucket = 256
  const int NG = NB * 64;                   // 4-node groups
  const int NWG = (E + CHUNK - 1) / CHUNK;

  char* p = (char*)d_ws;
  auto alloc = [&](size_t bytes) -> char* {
    char* r = p; p += (bytes + 255) & ~(size_t)255; return r;
  };
  int*            gcnt    = (int*)  alloc(NBMAX * 4);
  int*            bbase   = (int*)  alloc((NBMAX + 1) * 4);
  int*            gcur    = (int*)  alloc(NBMAX * 4);
  int*            wghist  = (int*)  alloc((size_t)NWG * NBMAX * 4);
  int*            offs    = (int*)  alloc((size_t)(N + 1) * 4);
  float*          nrm     = (float*)alloc((size_t)N * 4);
  int*            csr_src = (int*)  alloc((size_t)E * 4);
  int*            gslots  = (int*)  alloc((size_t)(NG + 1) * 4);
  int*            gof     = (int*)  alloc((size_t)(NG + 1) * 4);
  int*            sbsum   = (int*)  alloc(1024);
  unsigned*       pidx    = (unsigned*)alloc((size_t)2 * E * 4);  // padded slots (expected ~1.2E)
  unsigned short* Wt      = (unsigned short*)alloc(192 * 512 * 2);
  unsigned short* Wt2     = (unsigned short*)alloc(64 * 128 * 2);
  size_t pkbytes = (size_t)(N + 1) * 64 * 4;   // +1: zero padding row
  size_t bpbytes = (size_t)E * 8;
  char*           shared0 = alloc(pkbytes > bpbytes ? pkbytes : bpbytes);
  int2*           bpairs  = (int2*)shared0;          // dead after k_csr
  unsigned int*   pkA     = (unsigned int*)shared0;  // alias: born at k_ell/k_transform
  unsigned int*   pkB     = (unsigned int*)alloc(pkbytes);
  unsigned short* h0b     = (unsigned short*)alloc((size_t)N * 64 * 2);

  hipMemsetAsync(gcnt, 0, NBMAX * 4, stream);

  k_wprep<<<512, 192, 0, stream>>>(W1, Wy, Wt);
  k_wprep2<<<128, 64, 0, stream>>>(W2, Wt2);
  k_bhist<<<NWG, 256, 0, stream>>>(ei, E, NB, gcnt, wghist);
  k_bscan<<<1, 512, 0, stream>>>(gcnt, bbase, gcur, offs, NB, N);
  k_bucket<<<NWG, 256, 0, stream>>>(ei, wghist, gcur, bpairs, E, NB);
  k_csr<<<NB, 256, 0, stream>>>(bpairs, bbase, offs, nrm, csr_src, gslots, N);
  int nb2 = (NG + 1023) / 1024;
  k_scan1<<<nb2, 1024, 0, stream>>>(gslots, gof, sbsum, NG);
  k_scan2<<<1, 128, 0, stream>>>(sbsum, nb2);
  k_scan3<<<nb2, 1024, 0, stream>>>(gof, sbsum, NG);
  k_ell<<<NG, 64, 0, stream>>>(offs, csr_src, gof, pidx, pkA, pkB, N);
  k_transform<<<(N + 127) / 128, 256, 0, stream>>>(Wt, Wt2, X, b1, b2, nrm, pkA, h0b, N);

  for (int k = 0; k < 10; ++k) {
    const unsigned int* in  = (k & 1) ? pkB : pkA;
    unsigned int*       out = (k & 1) ? pkA : pkB;
    k_prop<<<(NG + 3) / 4, 256, 0, stream>>>(gof, pidx, in, out, h0b, nrm,
                                             (float*)d_out, N, NG, (k == 9) ? 1 : 0);
  }
}